// Round 6
// baseline (554.932 us; speedup 1.0000x reference)
//
#include <hip/hip_runtime.h>

// MeshConv R6 (resubmit after broker timeout): out = combined @ W.T + b.
//
// R5 post-mortem: fp16 staging REFUTED. (a) fp16 row = 64B = half a 128B HBM
// line -> every L3-miss gather fetches 2x useful bytes; f32 rows are exactly
// one full line (no amplification). (b) the staged image did NOT stay
// L3-resident (FETCH 358MB) -- the nt out-stream churns L3. (c) cvt pass cost
// ~45us + 128MB + dirty-image writebacks (WRITE 416MB). What WAS confirmed:
// delivered BW scales with occupancy (3.59 TB/s @16 waves -> 4.07 @~24), and
// the fenced 4-phase epilogue (4.25KB LDS) is correctness-proven.
//
// R6 = f32 gathers (R2-proven byte profile: FETCH 312, WRITE 250) +
//      small epilogue + occupancy:
//  (1) no staging, no cvt dispatch.
//  (2) __launch_bounds__(256,5): <=102 VGPR -> 5 waves/SIMD = 20 waves/CU
//      (R2: 108 VGPR -> 16). LDS 24.3KB -> 5 blocks/CU fits (121.5KB).
//  (3) single gather buffer, reused: af extracted from cb (cb then dead) ->
//      next tile's gather issues into cb, overlapping MFMA+epilogue. Halves
//      buffer VGPRs vs R2's cb+pb (80 -> 40).
//  (4) nbr indices pipelined 2 tiles ahead (cheap, 8 VGPRs).
// Diagnostic this round: if WRITE returns to ~250MB, R5's 416 was the fp16
// dirty image; if ~416 persists, the 4-phase epilogue is implicated.

typedef __bf16 bf16_t;
typedef __bf16 bf16x8 __attribute__((ext_vector_type(8)));
typedef float  f32x4  __attribute__((ext_vector_type(4)));

#define EC      1000000
#define CCH     32
#define OUTD    64
#define KD      160          // 5*CCH
#define MT      64           // elements per tile
#define NTILES  (EC / MT)    // 15625
#define NFRAG   1280         // 5 ks * 4 tn * 4 quad * 16 col frags of 8 bf16
#define TSTR    68           // epilogue LDS row stride (floats)
#define GRID    1280         // 5 blocks/CU * 256 CUs

__global__ __launch_bounds__(256, 5)
void meshconv_kernel(const float* __restrict__ x,
                     const int*   __restrict__ nbr,
                     const float* __restrict__ W,
                     const float* __restrict__ bias,
                     float*       __restrict__ out)
{
    __shared__ bf16_t w_lds[NFRAG * 8];                                // 20.0 KB
    __shared__ __attribute__((aligned(16))) float t_lds[4 * 4 * TSTR]; // 4.25 KB

    const int tid  = threadIdx.x;
    const int wave = tid >> 6;
    const int lane = tid & 63;
    const int col  = lane & 15;
    const int quad = lane >> 4;

    // ---- one-time: W (64x160 f32) -> bf16 LDS, frag-swizzled ----
    // frag(ks,tn,quad,col,j) = W[o = tn*16+col][k = ks*32 + quad*8 + j]
    for (int i = tid; i < NFRAG; i += 256) {
        const int fc  = i & 15;
        const int fq  = (i >> 4) & 3;
        const int ftn = (i >> 6) & 3;
        const int fks = i >> 8;
        const float* src = W + (ftn * 16 + fc) * KD + fks * 32 + fq * 8;
        f32x4 w0 = *(const f32x4*)src;
        f32x4 w1 = *(const f32x4*)(src + 4);
        bf16x8 wf;
        wf[0]=(bf16_t)w0[0]; wf[1]=(bf16_t)w0[1]; wf[2]=(bf16_t)w0[2]; wf[3]=(bf16_t)w0[3];
        wf[4]=(bf16_t)w1[0]; wf[5]=(bf16_t)w1[1]; wf[6]=(bf16_t)w1[2]; wf[7]=(bf16_t)w1[3];
        *(bf16x8*)&w_lds[i * 8] = wf;
    }

    float bv[4];
#pragma unroll
    for (int tn = 0; tn < 4; ++tn) bv[tn] = bias[tn * 16 + col];

    float* tw = &t_lds[wave * 4 * TSTR];   // per-wave 4-row region

    __syncthreads();   // w_lds ready; read-only hereafter

    auto ld_nbr = [&](int t) -> int4 {
        return ((const int4*)nbr)[t * MT + wave * 16 + col];
    };
    // 5 rows x 8 channels (this lane's quad slice). f32 row = 128B = exactly
    // one HBM line across the 4 quads of a col: no fetch amplification.
    auto gather = [&](int t, const int4& nb, f32x4* buf) {
        const int e  = t * MT + wave * 16 + col;
        const int i0 = nb.x < 0 ? 0 : nb.x;
        const int i1 = nb.y < 0 ? 0 : nb.y;
        const int i2 = nb.z < 0 ? 0 : nb.z;
        const int i3 = nb.w < 0 ? 0 : nb.w;
        const int co = quad * 8;
        const f32x4* p;
        p = (const f32x4*)(x + (size_t)e  * CCH + co); buf[0] = p[0]; buf[1] = p[1];
        p = (const f32x4*)(x + (size_t)i0 * CCH + co); buf[2] = p[0]; buf[3] = p[1];
        p = (const f32x4*)(x + (size_t)i1 * CCH + co); buf[4] = p[0]; buf[5] = p[1];
        p = (const f32x4*)(x + (size_t)i2 * CCH + co); buf[6] = p[0]; buf[7] = p[1];
        p = (const f32x4*)(x + (size_t)i3 * CCH + co); buf[8] = p[0]; buf[9] = p[1];
    };

    int tile = blockIdx.x;
    int4  nb_cur, nb_nxt;
    f32x4 cb[10];
    if (tile < NTILES) {
        nb_cur = ld_nbr(tile);                  // prologue: serial once
        gather(tile, nb_cur, cb);
        const int t1 = (tile + GRID < NTILES) ? tile + GRID : tile;
        nb_nxt = ld_nbr(t1);
    }

    for (; tile < NTILES; tile += GRID) {
        // ---- descriptor slices == the 5 A-frags; cb fully consumed here ----
        const float m0 = nb_cur.x < 0 ? 0.f : 1.f;
        const float m1 = nb_cur.y < 0 ? 0.f : 1.f;
        const float m2 = nb_cur.z < 0 ? 0.f : 1.f;
        const float m3 = nb_cur.w < 0 ? 0.f : 1.f;

        bf16x8 af[5];
#pragma unroll
        for (int h = 0; h < 2; ++h) {
#pragma unroll
            for (int j = 0; j < 4; ++j) {
                const int jj = h * 4 + j;
                const float va0 = cb[2 + h][j] * m0;
                const float va1 = cb[4 + h][j] * m1;
                const float vb0 = cb[6 + h][j] * m2;
                const float vb1 = cb[8 + h][j] * m3;
                const float sa = va0 + va1;
                const float da = fabsf(va0 - va1);
                const float sb = vb0 + vb1;
                const float db = fabsf(vb0 - vb1);
                af[0][jj] = (bf16_t)cb[h][j];
                af[1][jj] = (bf16_t)(sa + sb);
                af[2][jj] = (bf16_t)(da + db);
                af[3][jj] = (bf16_t)fabsf(sa - sb);
                af[4][jj] = (bf16_t)fabsf(da - db);
            }
        }

        // ---- cb is dead: issue next tile's gather into it NOW; the loads
        //      stay in flight through MFMA + epilogue (intra-wave overlap
        //      at single-buffer register cost) ----
        const int nxt = tile + GRID;
        int4 nb2 = nb_nxt;
        if (nxt < NTILES) {
            gather(nxt, nb_nxt, cb);
            const int t2 = (nxt + GRID < NTILES) ? nxt + GRID : nxt;
            nb2 = ld_nbr(t2);                   // nbr two tiles ahead
        }

        // ---- MFMA: acc[tn][r] = C(e-row = quad*4+r, o = tn*16+col) ----
        f32x4 acc[4] = {{0.f,0.f,0.f,0.f},{0.f,0.f,0.f,0.f},
                        {0.f,0.f,0.f,0.f},{0.f,0.f,0.f,0.f}};
#pragma unroll
        for (int ks = 0; ks < 5; ++ks) {
#pragma unroll
            for (int tn = 0; tn < 4; ++tn) {
                const bf16x8 bfr = *(const bf16x8*)&w_lds[(((ks*4+tn)*4+quad)*16 + col) * 8];
                acc[tn] = __builtin_amdgcn_mfma_f32_16x16x32_bf16(af[ks], bfr, acc[tn], 0, 0, 0);
            }
        }

        // ---- epilogue: 4-phase in-wave LDS transpose -> full-line nt stores.
        // Phase p: quad-p lanes (holding e-rows p*4..p*4+3) write their 16
        // values; ALL lanes read back (local row `quad` -> e-row p*4+quad).
        // asm fences stop GVN from CSE'ing the identical-address reads
        // (R4's bug, fixed+proven in R5). HW DS ops are in-order per wave.
        // Each nt store instruction covers 4 rows x 256B = 1KB contiguous.
#pragma unroll
        for (int p = 0; p < 4; ++p) {
            if (quad == p) {
#pragma unroll
                for (int tn = 0; tn < 4; ++tn)
#pragma unroll
                    for (int r = 0; r < 4; ++r)
                        tw[r * TSTR + tn * 16 + col] = acc[tn][r] + bv[tn];
            }
            asm volatile("" ::: "memory");   // stores above visible; no load CSE
            const f32x4 v = *(const f32x4*)&tw[quad * TSTR + col * 4];
            asm volatile("" ::: "memory");   // read done before next phase's writes
            float* op = out + (size_t)(tile * MT + wave * 16 + p * 4 + quad) * OUTD + col * 4;
            __builtin_nontemporal_store(v, (f32x4*)op);
        }

        // ---- rotate nbr pipeline (gather buffer already rotated in-place) ----
        nb_cur = nb_nxt;
        nb_nxt = nb2;
    }
}

extern "C" void kernel_launch(void* const* d_in, const int* in_sizes, int n_in,
                              void* d_out, int out_size, void* d_ws, size_t ws_size,
                              hipStream_t stream) {
    const float* x    = (const float*)d_in[0];
    const int*   nbr  = (const int*)d_in[1];
    const float* W    = (const float*)d_in[2];
    const float* bias = (const float*)d_in[3];
    float* out = (float*)d_out;
    // 1280 blocks = 5 resident blocks/CU x 256 CUs (LDS 24.3KB*5 = 121.5KB,
    // VGPR <=102 via launch_bounds). Grid-stride, ~12 tiles per block.
    meshconv_kernel<<<dim3(GRID), dim3(256), 0, stream>>>(x, nbr, W, bias, out);
}

// Round 8
// 414.598 us; speedup vs baseline: 1.3385x; 1.3385x over previous
//
#include <hip/hip_runtime.h>

// MeshConv R7 (resubmit after broker timeout): out = combined @ W.T + b.
//
// R6 post-mortem: the session-long anomaly was REGISTER SPILLING. Every kernel
// with __launch_bounds__(256, >=5) reported VGPR 40-48 vs a ~90+ live set ->
// scratch spills -> spill traffic at HBM (R6: FETCH +170MB, WRITE +370MB over
// the byte-exact profile) and VALUBusy collapse. The waves-per-EU bound snaps
// the VGPR budget to a coarse quantum (occupancy cliffs at 64/128/256), so
// requesting 5-6 waves/EU set a ~64-VGPR budget and cascaded. With a ~76-VGPR
// irreducible live set (af 20 + acc 16 + in-flight gather buffer 40), >16
// waves/CU is unreachable without spills. Occupancy is capped; optimize the
// wave instead.
//
// R7 = R0/R2 byte-exact structure (VGPR 108, FETCH 312, WRITE 250,000 KiB
// exact, dur 160us) + two surgical changes:
//  (1) nbr pipelined 2 tiles ahead: R2's prefetch serialized
//      nbr-load -> wait -> 10 gathers inside the loop body; now the gathers
//      issue immediately from a resident nbr (+~6 VGPR, still << 128 cap).
//  (2) GRID 1024 -> 2048: halves per-block grid-stride iters, smoothing
//      straggler blocks with slow random gathers.
// NO launch_bounds min-waves arg. NO fp16 staging. NO 4-phase epilogue.

typedef __bf16 bf16_t;
typedef __bf16 bf16x8 __attribute__((ext_vector_type(8)));
typedef float  f32x4  __attribute__((ext_vector_type(4)));

#define EC      1000000
#define CCH     32
#define OUTD    64
#define KD      160          // 5*CCH
#define MT      64           // elements per tile
#define NTILES  (EC / MT)    // 15625
#define NFRAG   1280         // 5 ks * 4 tn * 4 quad * 16 col frags of 8 bf16
#define TSTR    68           // epilogue LDS row stride (floats): 16B-aligned rows
#define GRID    2048

__global__ __launch_bounds__(256)
void meshconv_kernel(const float* __restrict__ x,
                     const int*   __restrict__ nbr,
                     const float* __restrict__ W,
                     const float* __restrict__ bias,
                     float*       __restrict__ out)
{
    __shared__ bf16_t w_lds[NFRAG * 8];                         // 20.0 KB
    __shared__ __attribute__((aligned(16))) float t_lds[4 * 16 * TSTR]; // 17.0 KB

    const int tid  = threadIdx.x;
    const int wave = tid >> 6;
    const int lane = tid & 63;
    const int col  = lane & 15;
    const int quad = lane >> 4;

    // ---- one-time: W (64x160 f32) -> bf16 LDS, frag-swizzled ----
    for (int i = tid; i < NFRAG; i += 256) {
        const int fc  = i & 15;
        const int fq  = (i >> 4) & 3;
        const int ftn = (i >> 6) & 3;
        const int fks = i >> 8;
        const float* src = W + (ftn * 16 + fc) * KD + fks * 32 + fq * 8;
        f32x4 w0 = *(const f32x4*)src;
        f32x4 w1 = *(const f32x4*)(src + 4);
        bf16x8 wf;
        wf[0]=(bf16_t)w0[0]; wf[1]=(bf16_t)w0[1]; wf[2]=(bf16_t)w0[2]; wf[3]=(bf16_t)w0[3];
        wf[4]=(bf16_t)w1[0]; wf[5]=(bf16_t)w1[1]; wf[6]=(bf16_t)w1[2]; wf[7]=(bf16_t)w1[3];
        *(bf16x8*)&w_lds[i * 8] = wf;
    }

    float bv[4];
#pragma unroll
    for (int tn = 0; tn < 4; ++tn) bv[tn] = bias[tn * 16 + col];

    float* tw = &t_lds[wave * 16 * TSTR];   // per-wave region, no cross-wave sharing

    __syncthreads();   // w_lds ready; read-only hereafter

    auto ld_nbr = [&](int t) -> int4 {
        return ((const int4*)nbr)[t * MT + wave * 16 + col];
    };
    // Gather one tile's 5 rows (channel slice [quad*8, quad*8+8)) using an
    // ALREADY-RESIDENT nbr int4: the 10 loads issue with no nbr wait.
    auto gather = [&](int t, const int4& nb, f32x4* buf) {
        const int e  = t * MT + wave * 16 + col;
        const int i0 = nb.x < 0 ? 0 : nb.x;
        const int i1 = nb.y < 0 ? 0 : nb.y;
        const int i2 = nb.z < 0 ? 0 : nb.z;
        const int i3 = nb.w < 0 ? 0 : nb.w;
        const int co = quad * 8;
        const f32x4* p;
        p = (const f32x4*)(x + (size_t)e  * CCH + co); buf[0] = p[0]; buf[1] = p[1];
        p = (const f32x4*)(x + (size_t)i0 * CCH + co); buf[2] = p[0]; buf[3] = p[1];
        p = (const f32x4*)(x + (size_t)i1 * CCH + co); buf[4] = p[0]; buf[5] = p[1];
        p = (const f32x4*)(x + (size_t)i2 * CCH + co); buf[6] = p[0]; buf[7] = p[1];
        p = (const f32x4*)(x + (size_t)i3 * CCH + co); buf[8] = p[0]; buf[9] = p[1];
    };

    int tile = blockIdx.x;
    int4  nb_cur, nb_nxt;          // nbr for tile (cur) and tile+GRID
    f32x4 cb[10];
    if (tile < NTILES) {
        nb_cur = ld_nbr(tile);                  // prologue: serial once
        gather(tile, nb_cur, cb);
        const int t1 = (tile + GRID < NTILES) ? tile + GRID : tile;
        nb_nxt = ld_nbr(t1);                    // in flight / resident for loop
    }

    for (; tile < NTILES; tile += GRID) {
        // ---- prefetch next tile: gathers issue IMMEDIATELY (nbr resident);
        //      nbr for tile+2*GRID issued now with no dependents this iter ----
        const int nxt = tile + GRID;
        int4  nb2 = nb_nxt;
        f32x4 pb[10];
        if (nxt < NTILES) {
            gather(nxt, nb_nxt, pb);
            const int t2 = (nxt + GRID < NTILES) ? nxt + GRID : nxt;
            nb2 = ld_nbr(t2);
        }

        // ---- descriptor slices == the 5 A-frags ----
        const float m0 = nb_cur.x < 0 ? 0.f : 1.f;
        const float m1 = nb_cur.y < 0 ? 0.f : 1.f;
        const float m2 = nb_cur.z < 0 ? 0.f : 1.f;
        const float m3 = nb_cur.w < 0 ? 0.f : 1.f;

        bf16x8 af[5];
#pragma unroll
        for (int h = 0; h < 2; ++h) {
#pragma unroll
            for (int j = 0; j < 4; ++j) {
                const int jj = h * 4 + j;
                const float va0 = cb[2 + h][j] * m0;
                const float va1 = cb[4 + h][j] * m1;
                const float vb0 = cb[6 + h][j] * m2;
                const float vb1 = cb[8 + h][j] * m3;
                const float sa = va0 + va1;
                const float da = fabsf(va0 - va1);
                const float sb = vb0 + vb1;
                const float db = fabsf(vb0 - vb1);
                af[0][jj] = (bf16_t)cb[h][j];
                af[1][jj] = (bf16_t)(sa + sb);
                af[2][jj] = (bf16_t)(da + db);
                af[3][jj] = (bf16_t)fabsf(sa - sb);
                af[4][jj] = (bf16_t)fabsf(da - db);
            }
        }

        // ---- MFMA: 16 rows x 64 cols per wave, K = 5 x 32 ----
        f32x4 acc[4] = {{0.f,0.f,0.f,0.f},{0.f,0.f,0.f,0.f},
                        {0.f,0.f,0.f,0.f},{0.f,0.f,0.f,0.f}};
#pragma unroll
        for (int ks = 0; ks < 5; ++ks) {
#pragma unroll
            for (int tn = 0; tn < 4; ++tn) {
                const bf16x8 bfr = *(const bf16x8*)&w_lds[(((ks*4+tn)*4+quad)*16 + col) * 8];
                acc[tn] = __builtin_amdgcn_mfma_f32_16x16x32_bf16(af[ks], bfr, acc[tn], 0, 0, 0);
            }
        }

        // ---- epilogue: in-wave LDS transpose -> full-line nt dwordx4 stores ----
        // acc[tn][r] = C(row=quad*4+r, col=tn*16+col) ; distinct read/write
        // addresses per thread (no CSE hazard; proven byte-exact: WRITE=250MB)
#pragma unroll
        for (int tn = 0; tn < 4; ++tn)
#pragma unroll
            for (int r = 0; r < 4; ++r)
                tw[(quad * 4 + r) * TSTR + tn * 16 + col] = acc[tn][r] + bv[tn];

#pragma unroll
        for (int r = 0; r < 4; ++r) {
            const f32x4 v = *(const f32x4*)&tw[(quad * 4 + r) * TSTR + col * 4];
            float* op = out + (size_t)(tile * MT + wave * 16 + quad * 4 + r) * OUTD + col * 4;
            __builtin_nontemporal_store(v, (f32x4*)op);
        }

        // ---- rotate pipeline ----
        nb_cur = nb_nxt;
        nb_nxt = nb2;
#pragma unroll
        for (int k = 0; k < 10; ++k) cb[k] = pb[k];
    }
}

extern "C" void kernel_launch(void* const* d_in, const int* in_sizes, int n_in,
                              void* d_out, int out_size, void* d_ws, size_t ws_size,
                              hipStream_t stream) {
    const float* x    = (const float*)d_in[0];
    const int*   nbr  = (const int*)d_in[1];
    const float* W    = (const float*)d_in[2];
    const float* bias = (const float*)d_in[3];
    float* out = (float*)d_out;
    // 2048 blocks, grid-stride ~7-8 tiles each: residency-limited blocks
    // backfill as stragglers finish (random gather latencies), shrinking the
    // tail vs 1024x15. No launch_bounds min-waves: avoids the VGPR-budget
    // quantum snap that caused spill cascades in R3/R5/R6.
    meshconv_kernel<<<dim3(GRID), dim3(256), 0, stream>>>(x, nbr, W, bias, out);
}